// Round 15
// baseline (465.388 us; speedup 1.0000x reference)
//
#include <hip/hip_runtime.h>
#include <math.h>

#define BB 8
#define PP 57744
#define NOBJ 20
#define CC 81
#define ROWS (BB*PP)
#define CONFBLK ((ROWS + 255) / 256)   // 1805 blocks, 256 threads, 1 row/lane
#define BPSPLIT 8
#define BPCHUNK (PP / BPSPLIT)         // 7218 exactly
#define SELBLK 128

// ws layout in 4-byte units
// cnt: [0]=num_pos [1]=sl1_sum(f) [2]=pos_ce(f) [3]=neg_ce(f) [4]=neg_cnt
//      [5]=eqCtr [10]=T [11]=eqSlots [12]=doneB [13]=negsum_done [14]=flagB
//      [15]=prefixAB [16]=KrC [17]=doneC [21]=flagD
#define W_CNT  0                        // 64 words
#define W_HA   64                       // 8 copies x 2048 bins (bits 31:21)
#define W_HB   (W_HA + 8*2048)          // 8 copies x 2048 (bits 20:10)
#define W_HC   (W_HB + 8*2048)          // 8 copies x 1024 (bits 9:0)
#define W_ZERO (W_HC + 8*1024)          // 41024 words zeroed by bp's stripe
#define W_BP   W_ZERO                   // 160*8 u64 slots (plain-stored)
#define W_KEY  (W_BP + 2560)            // ROWS uints
#define W_CE   (W_KEY + ROWS)           // ROWS floats

#define SCOPE_AGENT __HIP_MEMORY_SCOPE_AGENT
// Completion ordering only (no buffer_wbl2/buffer_inv cache maintenance —
// the round-5 410us lesson): prior vmem ops retired at the coherence point.
#define VMEM_DRAIN() asm volatile("s_waitcnt vmcnt(0) lgkmcnt(0)" ::: "memory")

__device__ __forceinline__ unsigned keymap(float f) {
    unsigned u = __float_as_uint(f);
    return (u & 0x80000000u) ? ~u : (u | 0x80000000u);
}

__device__ __forceinline__ float smooth_l1(float d) {
    float a = fabsf(d);
    return a < 1.f ? 0.5f * d * d : a - 0.5f;
}

__device__ __forceinline__ unsigned aload_u(const unsigned* p) {
    return __hip_atomic_load(p, __ATOMIC_RELAXED, SCOPE_AGENT);
}
__device__ __forceinline__ int aload_i(const int* p) {
    return __hip_atomic_load(p, __ATOMIC_RELAXED, SCOPE_AGENT);
}
__device__ __forceinline__ float aload_f(const float* p) {
    return __hip_atomic_load(p, __ATOMIC_RELAXED, SCOPE_AGENT);
}
__device__ __forceinline__ void astore_i(int* p, int v) {
    __hip_atomic_store(p, v, __ATOMIC_RELAXED, SCOPE_AGENT);
}

// Descending-cumulative threshold search over NB bins summed across 8 global
// copies. ATOMIC=false: plain cached loads — valid when the hist was written
// by a PRIOR kernel. ATOMIC=true: agent loads for same-kernel writes.
template <int NB, bool ATOMIC>
__device__ int scan_bins(const unsigned* __restrict__ h, unsigned Kr,
                         unsigned* rem_out) {
    constexpr int BPT = NB / 256;
    __shared__ unsigned stot[256];
    __shared__ int sbin;
    __shared__ unsigned srem;
    __syncthreads();                 // protect shared reuse across calls
    int i = threadIdx.x;
    unsigned v[BPT];
    unsigned tot = 0;
    #pragma unroll
    for (int j = 0; j < BPT; j++) {
        unsigned s = 0;
        #pragma unroll
        for (int c = 0; c < 8; c++) {
            const unsigned* p = h + c * NB + i * BPT + j;
            s += ATOMIC ? aload_u(p) : *p;
        }
        v[j] = s; tot += s;
    }
    if (i == 0) sbin = -1;
    stot[i] = tot; __syncthreads();
    for (int off = 1; off < 256; off <<= 1) {   // inclusive suffix scan
        unsigned add = (i + off < 256) ? stot[i + off] : 0u;
        __syncthreads(); stot[i] += add; __syncthreads();
    }
    unsigned cum = (i < 255) ? stot[i + 1] : 0u;
    #pragma unroll
    for (int j = BPT - 1; j >= 0; j--) {
        unsigned nxt = cum;      // suffix(bin+1)
        cum += v[j];             // suffix(bin)
        if (cum >= Kr && nxt < Kr) { sbin = i * BPT + j; srem = Kr - nxt; }
    }
    __syncthreads();
    *rem_out = (sbin >= 0) ? srem : 0u;
    return sbin;
}

// Grid (NOBJ, BB, BPSPLIT): per-(gt,batch,chunk) argmax over a prior chunk,
// packed (iou_bits<<32)|(~p). Plain per-slot store (written once, no init).
// Also zeroes cnt+hist regions, replacing the memset launch (r14-proven).
__global__ void k_best_prior(const float* __restrict__ priors,
                             const float* __restrict__ gt,
                             unsigned long long* __restrict__ bp8,
                             int* __restrict__ ws) {
    int n = blockIdx.x, b = blockIdx.y, z = blockIdx.z;
    int bid = n + NOBJ * (b + BB * z);
    int gz = bid * 256 + threadIdx.x;
    if (gz < W_ZERO) ws[gz] = 0;

    int p0 = z * BPCHUNK;
    int p1 = p0 + BPCHUNK;
    const float* t = gt + (b * NOBJ + n) * 4;
    float tx1 = t[0], ty1 = t[1], tx2 = t[2], ty2 = t[3];
    float ta = (tx2 - tx1) * (ty2 - ty1);
    unsigned long long best = 0ull;
    for (int p = p0 + threadIdx.x; p < p1; p += 256) {
        float4 pr = ((const float4*)priors)[p];
        float px1 = pr.x - pr.z * 0.5f, py1 = pr.y - pr.w * 0.5f;
        float px2 = pr.x + pr.z * 0.5f, py2 = pr.y + pr.w * 0.5f;
        float iw = fmaxf(fminf(tx2, px2) - fmaxf(tx1, px1), 0.f);
        float ih = fmaxf(fminf(ty2, py2) - fmaxf(ty1, py1), 0.f);
        float inter = iw * ih;
        float iou = inter / (ta + (px2 - px1) * (py2 - py1) - inter);
        unsigned long long pk = ((unsigned long long)__float_as_uint(iou) << 32)
                              | (unsigned long long)(0xFFFFFFFFu - (unsigned)p);
        if (pk > best) best = pk;
    }
    __shared__ unsigned long long sb[256];
    int tid = threadIdx.x;
    sb[tid] = best; __syncthreads();
    for (int s = 128; s > 0; s >>= 1) {
        if (tid < s && sb[tid + s] > sb[tid]) sb[tid] = sb[tid + s];
        __syncthreads();
    }
    if (tid == 0) bp8[(b * NOBJ + n) * BPSPLIT + z] = sb[0];
}

// FUSED match + softmax CE + key + level-A hist, row-per-lane, no staging.
// Per lane: own row from global (r12-proven ~100us pattern), own prior
// (coalesced float4), in-lane 20-GT IoU argmax (tie->first) + force-match
// (last gt wins) against LDS-broadcast tables, ct in-register (conf_t array
// eliminated), smooth-L1 for rare positives with ballot-gated wave-reduced
// atomics. r7's fusion regression was into the 4-lane/LDS-staged structure;
// this one fills the 90% idle VALU of the row-per-lane kernel instead.
__global__ void __launch_bounds__(256) k_conf(const float* __restrict__ conf_data,
                                              const float* __restrict__ loc_data,
                                              const float* __restrict__ priors,
                                              const float* __restrict__ gt,
                                              const int* __restrict__ labels,
                                              const unsigned long long* __restrict__ bp8,
                                              unsigned* __restrict__ key,
                                              float* __restrict__ ce,
                                              float* __restrict__ cnt_f,
                                              int* __restrict__ cnt_i,
                                              unsigned* __restrict__ hA) {
    __shared__ unsigned lhist[2048];
    __shared__ float st2[2][NOBJ][4];
    __shared__ int slab2[2][NOBJ], sbp2[2][NOBJ];
    int tid = threadIdx.x;
    int row0 = blockIdx.x * 256;
    int b0 = row0 / PP;                  // block spans at most 2 batches

    for (int j = tid; j < 2048; j += 256) lhist[j] = 0;
    if (tid < 2 * NOBJ * 4 && b0 * NOBJ * 4 + tid < BB * NOBJ * 4)
        ((float*)st2)[tid] = gt[b0 * NOBJ * 4 + tid];
    if (tid < 2 * NOBJ && b0 * NOBJ + tid < BB * NOBJ) {
        ((int*)slab2)[tid] = labels[b0 * NOBJ + tid];
        unsigned long long m = 0ull;
        #pragma unroll
        for (int z = 0; z < BPSPLIT; z++) {
            unsigned long long v = bp8[(b0 * NOBJ + tid) * BPSPLIT + z];
            if (v > m) m = v;
        }
        ((int*)sbp2)[tid] = (int)(0xFFFFFFFFu - (unsigned)m);
    }
    __syncthreads();

    int row = row0 + tid;
    bool act = row < ROWS;
    int rr = act ? row : ROWS - 1;
    const float* x = conf_data + (size_t)rr * CC;

    float4 v[20];
    #pragma unroll
    for (int j = 0; j < 20; j++) __builtin_memcpy(&v[j], x + 4 * j, 16);
    float x80 = x[80];

    // ---- in-lane match ----
    int bi = (rr >= (b0 + 1) * PP) ? 1 : 0;
    int p = rr - (b0 + bi) * PP;
    float4 pr = ((const float4*)priors)[p];
    float px1 = pr.x - pr.z * 0.5f, py1 = pr.y - pr.w * 0.5f;
    float px2 = pr.x + pr.z * 0.5f, py2 = pr.y + pr.w * 0.5f;
    float pa = (px2 - px1) * (py2 - py1);
    float best = -1.f; int bn = 0;
    #pragma unroll
    for (int n = 0; n < NOBJ; n++) {
        float tx1 = st2[bi][n][0], ty1 = st2[bi][n][1];
        float tx2 = st2[bi][n][2], ty2 = st2[bi][n][3];
        float iw = fmaxf(fminf(tx2, px2) - fmaxf(tx1, px1), 0.f);
        float ih = fmaxf(fminf(ty2, py2) - fmaxf(ty1, py1), 0.f);
        float inter = iw * ih;
        float iou = inter / ((tx2 - tx1) * (ty2 - ty1) + pa - inter);
        if (iou > best) { best = iou; bn = n; }  // tie -> first n
    }
    float ov = best;
    #pragma unroll
    for (int n = 0; n < NOBJ; n++)
        if (sbp2[bi][n] == p) { bn = n; ov = 2.0f; }  // last n wins
    int ct = slab2[bi][bn];
    if (ov < 0.5f) ct = -1;
    if (ov < 0.4f) ct = 0;

    // ---- softmax (r12-proven math) ----
    float f0 = v[0].y, f1 = v[0].z, f2 = v[0].w, f3 = x80;
    #pragma unroll
    for (int j = 1; j < 20; j++) {
        f0 = fmaxf(f0, v[j].x);
        f1 = fmaxf(f1, v[j].y);
        f2 = fmaxf(f2, v[j].z);
        f3 = fmaxf(f3, v[j].w);
    }
    float fg = fmaxf(fmaxf(f0, f1), fmaxf(f2, f3));
    float m = fmaxf(fg, v[0].x);

    const float LOG2E = 1.4426950408889634f;
    float e0 = 0.f, e1 = 0.f, e2 = 0.f, e3 = 0.f;
    #pragma unroll
    for (int j = 0; j < 20; j++) {
        e0 += exp2f((v[j].x - m) * LOG2E);
        e1 += exp2f((v[j].y - m) * LOG2E);
        e2 += exp2f((v[j].z - m) * LOG2E);
        e3 += exp2f((v[j].w - m) * LOG2E);
    }
    float e = (e0 + e1) + (e2 + e3) + exp2f((x80 - m) * LOG2E);

    float lse = m + log2f(e) * 0.6931471805599453f;
    // ct<=0 -> clamp(ct)=0 -> x[0] is already in v[0].x; positives re-fetch
    float xc = (ct > 0) ? x[ct] : v[0].x;
    float cev = lse - xc;

    // ---- outputs ----
    float s_l1 = 0.f;
    bool pos = act && ct > 0;
    if (pos) {
        float mx1 = st2[bi][bn][0], my1 = st2[bi][bn][1];
        float mx2 = st2[bi][bn][2], my2 = st2[bi][bn][3];
        float gcx = ((mx1 + mx2) * 0.5f - pr.x) / (0.1f * pr.z);
        float gcy = ((my1 + my2) * 0.5f - pr.y) / (0.1f * pr.w);
        float gw = logf((mx2 - mx1) / pr.z) / 0.2f;
        float gh = logf((my2 - my1) / pr.w) / 0.2f;
        float4 ld = ((const float4*)loc_data)[rr];
        s_l1 = smooth_l1(ld.x - gcx) + smooth_l1(ld.y - gcy) +
               smooth_l1(ld.z - gw) + smooth_l1(ld.w - gh);
    }
    if (act) {
        ce[row] = cev;
        unsigned kv = (ct == 0) ? keymap(fg) : 0u;
        key[row] = kv;
        if (ct == 0) atomicAdd(&lhist[kv >> 21], 1u);
    }
    // positives are ~1e-3 of rows: ballot-gated wave reduction, most waves skip
    unsigned long long bal = __ballot(pos);
    if (bal) {
        float sl = pos ? s_l1 : 0.f;
        float pc = pos ? cev : 0.f;
        #pragma unroll
        for (int off = 32; off > 0; off >>= 1) {
            sl += __shfl_xor(sl, off);
            pc += __shfl_xor(pc, off);
        }
        if ((tid & 63) == 0) {
            atomicAdd(&cnt_i[0], (int)__popcll(bal));
            atomicAdd(&cnt_f[1], sl);
            atomicAdd(&cnt_f[2], pc);
        }
    }
    __syncthreads();
    unsigned* hmy = hA + (blockIdx.x & 7) * 2048;
    for (int j = tid; j < 2048; j += 256)
        if (lhist[j]) atomicAdd(&hmy[j], lhist[j]);
}

// Fused selection (r13/r14-proven): scan-A (plain loads on prior-kernel hA)
// -> phase-B hist -> last-block scan+publish -> phase-C hist -> last-block
// scan+publish -> negative-CE sum -> fused final. Relaxed agent atomics +
// vmcnt(0) completion only. 128 co-resident blocks.
__global__ void __launch_bounds__(256) k_sel(const unsigned* __restrict__ key,
                                             const float* __restrict__ ce,
                                             int* __restrict__ cnt_i,
                                             float* __restrict__ cnt_f,
                                             const unsigned* __restrict__ hA,
                                             unsigned* __restrict__ hB,
                                             unsigned* __restrict__ hC,
                                             float* __restrict__ out) {
    __shared__ unsigned lh[2048];
    __shared__ int amLast;
    int tid = threadIdx.x;
    const uint4* k4 = (const uint4*)key;
    int n4 = ROWS / 4;

    unsigned T = 0xFFFFFFFFu; int eqS = 0;
    unsigned Kr = 3u * (unsigned)cnt_i[0];
    bool decided = (Kr == 0);            // no positives: select none
    unsigned prefixA = 0, remB = 0;
    if (!decided) {
        int binA = scan_bins<2048, false>(hA, Kr, &remB);
        if (binA < 0) { T = 0u; eqS = 0; decided = true; }  // select all
        else prefixA = (unsigned)binA;
    }

    if (!decided) {
        // ---- phase B: bits 20:10 within prefixA ----
        for (int j = tid; j < 2048; j += 256) lh[j] = 0;
        __syncthreads();
        for (int r = blockIdx.x * 256 + tid; r < n4; r += gridDim.x * 256) {
            uint4 k = k4[r];
            if ((k.x >> 21) == prefixA) atomicAdd(&lh[(k.x >> 10) & 0x7FFu], 1u);
            if ((k.y >> 21) == prefixA) atomicAdd(&lh[(k.y >> 10) & 0x7FFu], 1u);
            if ((k.z >> 21) == prefixA) atomicAdd(&lh[(k.z >> 10) & 0x7FFu], 1u);
            if ((k.w >> 21) == prefixA) atomicAdd(&lh[(k.w >> 10) & 0x7FFu], 1u);
        }
        __syncthreads();
        {
            unsigned* hmy = hB + (blockIdx.x & 7) * 2048;
            for (int j = tid; j < 2048; j += 256)
                if (lh[j]) atomicAdd(&hmy[j], lh[j]);
        }
        VMEM_DRAIN();
        if (tid == 0)
            amLast = (__hip_atomic_fetch_add((unsigned*)&cnt_i[12], 1u,
                       __ATOMIC_RELAXED, SCOPE_AGENT) == (unsigned)(gridDim.x - 1));
        __syncthreads();
        if (amLast) {
            unsigned remC; int binB = scan_bins<2048, true>(hB, remB, &remC);
            if (binB < 0) { binB = 0; remC = 0; }   // defensive
            if (tid == 0) {
                astore_i(&cnt_i[15], (int)((prefixA << 11) | (unsigned)binB));
                astore_i(&cnt_i[16], (int)remC);
                VMEM_DRAIN();
                astore_i(&cnt_i[14], 1);  // flagB
            }
        }
        if (tid == 0) {
            while (aload_i(&cnt_i[14]) == 0) __builtin_amdgcn_s_sleep(8);
        }
        __syncthreads();
        unsigned prefixAB = (unsigned)aload_i(&cnt_i[15]);
        unsigned KrC = (unsigned)aload_i(&cnt_i[16]);

        // ---- phase C: bits 9:0 within prefixAB ----
        for (int j = tid; j < 1024; j += 256) lh[j] = 0;
        __syncthreads();
        for (int r = blockIdx.x * 256 + tid; r < n4; r += gridDim.x * 256) {
            uint4 k = k4[r];
            if ((k.x >> 10) == prefixAB) atomicAdd(&lh[k.x & 0x3FFu], 1u);
            if ((k.y >> 10) == prefixAB) atomicAdd(&lh[k.y & 0x3FFu], 1u);
            if ((k.z >> 10) == prefixAB) atomicAdd(&lh[k.z & 0x3FFu], 1u);
            if ((k.w >> 10) == prefixAB) atomicAdd(&lh[k.w & 0x3FFu], 1u);
        }
        __syncthreads();
        {
            unsigned* hmy = hC + (blockIdx.x & 7) * 1024;
            for (int j = tid; j < 1024; j += 256)
                if (lh[j]) atomicAdd(&hmy[j], lh[j]);
        }
        VMEM_DRAIN();
        if (tid == 0)
            amLast = (__hip_atomic_fetch_add((unsigned*)&cnt_i[17], 1u,
                       __ATOMIC_RELAXED, SCOPE_AGENT) == (unsigned)(gridDim.x - 1));
        __syncthreads();
        if (amLast) {
            unsigned remD; int binC = scan_bins<1024, true>(hC, KrC, &remD);
            if (binC < 0) { binC = 0; remD = 0; }   // defensive
            if (tid == 0) {
                astore_i(&cnt_i[10], (int)((prefixAB << 10) | (unsigned)binC));
                astore_i(&cnt_i[11], (int)remD);
                VMEM_DRAIN();
                astore_i(&cnt_i[21], 1);  // flagD
            }
        }
        if (tid == 0) {
            while (aload_i(&cnt_i[21]) == 0) __builtin_amdgcn_s_sleep(8);
        }
        __syncthreads();
        T = (unsigned)aload_i(&cnt_i[10]);
        eqS = aload_i(&cnt_i[11]);
    }

    // ---- negative-CE sum over selected (key > T, or == T up to eqS) ----
    float s = 0.f; int c = 0;
    for (int r = blockIdx.x * 256 + tid; r < n4; r += gridDim.x * 256) {
        uint4 k = k4[r];
        #define DO_ONE(comp, idx) { \
            unsigned kk = k.comp; \
            if (kk) { \
                bool selr = false; \
                if (kk > T) selr = true; \
                else if (kk == T) { int slot = atomicAdd(&cnt_i[5], 1); selr = slot < eqS; } \
                if (selr) { s += ce[4 * r + idx]; c++; } \
            } }
        DO_ONE(x, 0) DO_ONE(y, 1) DO_ONE(z, 2) DO_ONE(w, 3)
        #undef DO_ONE
    }
    __shared__ float rs[256]; __shared__ int rc[256];
    rs[tid] = s; rc[tid] = c; __syncthreads();
    for (int st = 128; st > 0; st >>= 1) {
        if (tid < st) { rs[tid] += rs[tid + st]; rc[tid] += rc[tid + st]; }
        __syncthreads();
    }
    if (tid == 0) {
        if (rs[0] != 0.f) atomicAdd(&cnt_f[3], rs[0]);
        if (rc[0])        atomicAdd(&cnt_i[4], rc[0]);
    }
    VMEM_DRAIN();   // my partial sums are at the coherence point
    if (tid == 0 &&
        __hip_atomic_fetch_add((unsigned*)&cnt_i[13], 1u,
            __ATOMIC_RELAXED, SCOPE_AGENT) == (unsigned)(gridDim.x - 1)) {
        int np = aload_i(&cnt_i[0]);
        int nn = aload_i(&cnt_i[4]);
        float f1 = aload_f(&cnt_f[1]);
        float f2 = aload_f(&cnt_f[2]);
        float f3 = aload_f(&cnt_f[3]);
        out[0] = f1 / (float)max(np, 1);
        out[1] = (f2 + f3) / (float)max(np + nn, 1);
    }
}

extern "C" void kernel_launch(void* const* d_in, const int* in_sizes, int n_in,
                              void* d_out, int out_size, void* d_ws, size_t ws_size,
                              hipStream_t stream) {
    const float* loc    = (const float*)d_in[0];
    const float* conf   = (const float*)d_in[1];
    const float* priors = (const float*)d_in[2];
    const float* gt     = (const float*)d_in[3];
    const int*   labels = (const int*)d_in[4];
    float* out = (float*)d_out;
    int*      wi = (int*)d_ws;
    float*    wf = (float*)d_ws;
    unsigned* wu = (unsigned*)d_ws;
    unsigned long long* wbp = (unsigned long long*)(wi + W_BP);

    // no memset: k_best_prior zeroes cnt+hists; bp slots are plain-stored
    k_best_prior<<<dim3(NOBJ, BB, BPSPLIT), 256, 0, stream>>>(priors, gt, wbp, wi);
    k_conf<<<CONFBLK, 256, 0, stream>>>(conf, loc, priors, gt, labels, wbp,
                                        wu + W_KEY, wf + W_CE, wf, wi, wu + W_HA);
    k_sel<<<SELBLK, 256, 0, stream>>>(wu + W_KEY, wf + W_CE, wi, wf,
                                      wu + W_HA, wu + W_HB, wu + W_HC, out);
}

// Round 16
// 359.802 us; speedup vs baseline: 1.2935x; 1.2935x over previous
//
#include <hip/hip_runtime.h>
#include <math.h>

#define BB 8
#define PP 57744
#define NOBJ 20
#define CC 81
#define ROWS (BB*PP)
#define CONFBLK ((ROWS + 255) / 256)   // 1805 blocks, 256 threads, 1 row/lane
#define BPSPLIT 8
#define BPCHUNK (PP / BPSPLIT)         // 7218 exactly (8*7218 == 57744)
#define SELBLK 128   // co-resident; fewer spin participants

// ws layout in 4-byte units
// cnt: [0]=num_pos [1]=sl1_sum(f) [2]=pos_ce(f) [3]=neg_ce(f) [4]=neg_cnt
//      [5]=eqCtr [10]=T [11]=eqSlots [12]=doneB [13]=negsum_done [14]=flagB
//      [15]=prefixAB [16]=KrC [17]=doneC [21]=flagD
#define W_CNT  0                        // 64 words
#define W_HA   64                       // 8 copies x 2048 bins (bits 31:21)
#define W_HB   (W_HA + 8*2048)          // 8 copies x 2048 (bits 20:10)
#define W_HC   (W_HB + 8*2048)          // 8 copies x 1024 (bits 9:0)
#define W_ZERO (W_HC + 8*1024)          // 41024 words: everything above is
                                        // zeroed by k_best_prior's stripe
#define W_BP   W_ZERO                   // 160*8 u64 slots = 2560 words
                                        // (plain-stored, no init needed)
#define W_CONF (W_BP + 2560)            // ROWS ints
#define W_KEY  (W_CONF + ROWS)          // ROWS uints
#define W_CE   (W_KEY + ROWS)           // ROWS floats

#define SCOPE_AGENT __HIP_MEMORY_SCOPE_AGENT
// Completion ordering only (no buffer_wbl2/buffer_inv cache maintenance —
// the round-5 410us lesson): prior vmem ops retired at the coherence point.
#define VMEM_DRAIN() asm volatile("s_waitcnt vmcnt(0) lgkmcnt(0)" ::: "memory")

__device__ __forceinline__ unsigned keymap(float f) {
    unsigned u = __float_as_uint(f);
    return (u & 0x80000000u) ? ~u : (u | 0x80000000u);
}

__device__ __forceinline__ float smooth_l1(float d) {
    float a = fabsf(d);
    return a < 1.f ? 0.5f * d * d : a - 0.5f;
}

__device__ __forceinline__ unsigned aload_u(const unsigned* p) {
    return __hip_atomic_load(p, __ATOMIC_RELAXED, SCOPE_AGENT);
}
__device__ __forceinline__ int aload_i(const int* p) {
    return __hip_atomic_load(p, __ATOMIC_RELAXED, SCOPE_AGENT);
}
__device__ __forceinline__ float aload_f(const float* p) {
    return __hip_atomic_load(p, __ATOMIC_RELAXED, SCOPE_AGENT);
}
__device__ __forceinline__ void astore_i(int* p, int v) {
    __hip_atomic_store(p, v, __ATOMIC_RELAXED, SCOPE_AGENT);
}

// Descending-cumulative threshold search over NB bins summed across 8 global
// copies. ATOMIC=false: plain cached loads — ONLY valid when the hist was
// written by a PRIOR kernel (dispatch boundary = coherence). ATOMIC=true:
// agent-scope loads — required when reading same-kernel writes (k_sel's
// last-block scans). Deterministic given identical inputs.
template <int NB, bool ATOMIC>
__device__ int scan_bins(const unsigned* __restrict__ h, unsigned Kr,
                         unsigned* rem_out) {
    constexpr int BPT = NB / 256;
    __shared__ unsigned stot[256];
    __shared__ int sbin;
    __shared__ unsigned srem;
    __syncthreads();                 // protect shared reuse across calls
    int i = threadIdx.x;
    unsigned v[BPT];
    unsigned tot = 0;
    #pragma unroll
    for (int j = 0; j < BPT; j++) {
        unsigned s = 0;
        #pragma unroll
        for (int c = 0; c < 8; c++) {
            const unsigned* p = h + c * NB + i * BPT + j;
            s += ATOMIC ? aload_u(p) : *p;
        }
        v[j] = s; tot += s;
    }
    if (i == 0) sbin = -1;
    stot[i] = tot; __syncthreads();
    for (int off = 1; off < 256; off <<= 1) {   // inclusive suffix scan
        unsigned add = (i + off < 256) ? stot[i + off] : 0u;
        __syncthreads(); stot[i] += add; __syncthreads();
    }
    unsigned cum = (i < 255) ? stot[i + 1] : 0u;
    #pragma unroll
    for (int j = BPT - 1; j >= 0; j--) {
        unsigned nxt = cum;      // suffix(bin+1)
        cum += v[j];             // suffix(bin)
        if (cum >= Kr && nxt < Kr) { sbin = i * BPT + j; srem = Kr - nxt; }
    }
    __syncthreads();
    *rem_out = (sbin >= 0) ? srem : 0u;
    return sbin;
}

// Grid (NOBJ, BB, BPSPLIT): per-(gt,batch,chunk) argmax over a prior chunk,
// packed (iou_bits<<32)|(~p). Each block PLAIN-STORES its own slot (written
// exactly once; no atomicMax, no init dependency — poison-safe). Also zeroes
// the cnt+hist regions (bp never touches them; the kernel boundary publishes
// the zeros to match/conf/sel) — replaces the hipMemsetAsync launch.
__global__ void k_best_prior(const float* __restrict__ priors,
                             const float* __restrict__ gt,
                             unsigned long long* __restrict__ bp8,
                             int* __restrict__ ws) {
    int n = blockIdx.x, b = blockIdx.y, z = blockIdx.z;
    // zero stripe: blocks cover W_ZERO words of counters+hists
    int bid = n + NOBJ * (b + BB * z);
    int gz = bid * 256 + threadIdx.x;
    if (gz < W_ZERO) ws[gz] = 0;

    int p0 = z * BPCHUNK;
    int p1 = p0 + BPCHUNK;
    const float* t = gt + (b * NOBJ + n) * 4;
    float tx1 = t[0], ty1 = t[1], tx2 = t[2], ty2 = t[3];
    float ta = (tx2 - tx1) * (ty2 - ty1);
    unsigned long long best = 0ull;
    for (int p = p0 + threadIdx.x; p < p1; p += 256) {
        float4 pr = ((const float4*)priors)[p];
        float px1 = pr.x - pr.z * 0.5f, py1 = pr.y - pr.w * 0.5f;
        float px2 = pr.x + pr.z * 0.5f, py2 = pr.y + pr.w * 0.5f;
        float iw = fmaxf(fminf(tx2, px2) - fmaxf(tx1, px1), 0.f);
        float ih = fmaxf(fminf(ty2, py2) - fmaxf(ty1, py1), 0.f);
        float inter = iw * ih;
        float iou = inter / (ta + (px2 - px1) * (py2 - py1) - inter);
        unsigned long long pk = ((unsigned long long)__float_as_uint(iou) << 32)
                              | (unsigned long long)(0xFFFFFFFFu - (unsigned)p);
        if (pk > best) best = pk;
    }
    __shared__ unsigned long long sb[256];
    int tid = threadIdx.x;
    sb[tid] = best; __syncthreads();
    for (int s = 128; s > 0; s >>= 1) {
        if (tid < s && sb[tid + s] > sb[tid]) sb[tid] = sb[tid + s];
        __syncthreads();
    }
    if (tid == 0) bp8[(b * NOBJ + n) * BPSPLIT + z] = sb[0];
}

// Per prior: best truth (argmax over 20, tie->first), force-match (last gt wins),
// conf_t, and smooth-L1 loc loss for positives. Staging reduces the 8 bp
// slots per (b,n) to the global best prior index. Kept as a SEPARATE kernel:
// fusing it into k_conf regressed 3x across rounds 7/15 (breaks the row-load
// pipelining of the row-per-lane conf structure).
__global__ void k_match(const float* __restrict__ loc_data,
                        const float* __restrict__ priors,
                        const float* __restrict__ gt,
                        const int* __restrict__ labels,
                        const unsigned long long* __restrict__ bp8,
                        int* __restrict__ conf_t,
                        float* __restrict__ cnt_f,
                        int* __restrict__ cnt_i) {
    int b = blockIdx.y;
    int tid = threadIdx.x;
    int p = blockIdx.x * 256 + tid;
    __shared__ float st[NOBJ][4];
    __shared__ int slab[NOBJ], sbp[NOBJ];
    if (tid < NOBJ * 4) ((float*)st)[tid] = gt[b * NOBJ * 4 + tid];
    if (tid < NOBJ) {
        slab[tid] = labels[b * NOBJ + tid];
        unsigned long long m = 0ull;
        #pragma unroll
        for (int z = 0; z < BPSPLIT; z++) {
            unsigned long long v = bp8[(b * NOBJ + tid) * BPSPLIT + z];
            if (v > m) m = v;
        }
        sbp[tid] = (int)(0xFFFFFFFFu - (unsigned)m);
    }
    __syncthreads();
    float s_l1 = 0.f; int is_pos = 0;
    if (p < PP) {
        float4 pr = ((const float4*)priors)[p];
        float px1 = pr.x - pr.z * 0.5f, py1 = pr.y - pr.w * 0.5f;
        float px2 = pr.x + pr.z * 0.5f, py2 = pr.y + pr.w * 0.5f;
        float pa = (px2 - px1) * (py2 - py1);
        float best = -1.f; int bn = 0;
        for (int n = 0; n < NOBJ; n++) {
            float tx1 = st[n][0], ty1 = st[n][1], tx2 = st[n][2], ty2 = st[n][3];
            float iw = fmaxf(fminf(tx2, px2) - fmaxf(tx1, px1), 0.f);
            float ih = fmaxf(fminf(ty2, py2) - fmaxf(ty1, py1), 0.f);
            float inter = iw * ih;
            float iou = inter / ((tx2 - tx1) * (ty2 - ty1) + pa - inter);
            if (iou > best) { best = iou; bn = n; }  // tie -> first n
        }
        float ov = best;
        for (int n = 0; n < NOBJ; n++)
            if (sbp[n] == p) { bn = n; ov = 2.0f; }  // last n wins
        int conf = slab[bn];
        if (ov < 0.5f) conf = -1;
        if (ov < 0.4f) conf = 0;
        conf_t[b * PP + p] = conf;
        if (conf > 0) {
            is_pos = 1;
            float mx1 = st[bn][0], my1 = st[bn][1], mx2 = st[bn][2], my2 = st[bn][3];
            float gcx = ((mx1 + mx2) * 0.5f - pr.x) / (0.1f * pr.z);
            float gcy = ((my1 + my2) * 0.5f - pr.y) / (0.1f * pr.w);
            float gw = logf((mx2 - mx1) / pr.z) / 0.2f;
            float gh = logf((my2 - my1) / pr.w) / 0.2f;
            float4 ld = ((const float4*)loc_data)[b * PP + p];
            s_l1 = smooth_l1(ld.x - gcx) + smooth_l1(ld.y - gcy) +
                   smooth_l1(ld.z - gw) + smooth_l1(ld.w - gh);
        }
    }
    __shared__ float rs[256]; __shared__ int rc[256];
    rs[tid] = s_l1; rc[tid] = is_pos; __syncthreads();
    for (int s = 128; s > 0; s >>= 1) {
        if (tid < s) { rs[tid] += rs[tid + s]; rc[tid] += rc[tid + s]; }
        __syncthreads();
    }
    if (tid == 0) {
        if (rs[0] != 0.f) atomicAdd(&cnt_f[1], rs[0]);
        if (rc[0])        atomicAdd(&cnt_i[0], rc[0]);
    }
}

// ROW-PER-LANE, NO LDS staging (r12, ~100us) + FUSED level-A histogram:
// per-block 2048-bin LDS hist of key>>21 (LDS atomics), flushed once per
// block to 8 spread global copies (r3/r4-proven pattern; measured free).
__global__ void __launch_bounds__(256) k_conf(const float* __restrict__ conf_data,
                                              const int* __restrict__ conf_t,
                                              unsigned* __restrict__ key,
                                              float* __restrict__ ce,
                                              float* __restrict__ cnt_f,
                                              unsigned* __restrict__ hA) {
    __shared__ unsigned lhist[2048];
    int tid = threadIdx.x;
    for (int j = tid; j < 2048; j += 256) lhist[j] = 0;
    __syncthreads();

    int row = blockIdx.x * 256 + tid;
    bool act = row < ROWS;
    int rr = act ? row : ROWS - 1;
    const float* x = conf_data + (size_t)rr * CC;
    int ct = conf_t[rr];

    float4 v[20];
    #pragma unroll
    for (int j = 0; j < 20; j++) __builtin_memcpy(&v[j], x + 4 * j, 16);
    float x80 = x[80];

    // fg = max over classes 1..80 (4 accumulators for ILP)
    float f0 = v[0].y, f1 = v[0].z, f2 = v[0].w, f3 = x80;
    #pragma unroll
    for (int j = 1; j < 20; j++) {
        f0 = fmaxf(f0, v[j].x);
        f1 = fmaxf(f1, v[j].y);
        f2 = fmaxf(f2, v[j].z);
        f3 = fmaxf(f3, v[j].w);
    }
    float fg = fmaxf(fmaxf(f0, f1), fmaxf(f2, f3));
    float m = fmaxf(fg, v[0].x);

    const float LOG2E = 1.4426950408889634f;
    float e0 = 0.f, e1 = 0.f, e2 = 0.f, e3 = 0.f;
    #pragma unroll
    for (int j = 0; j < 20; j++) {
        e0 += exp2f((v[j].x - m) * LOG2E);
        e1 += exp2f((v[j].y - m) * LOG2E);
        e2 += exp2f((v[j].z - m) * LOG2E);
        e3 += exp2f((v[j].w - m) * LOG2E);
    }
    float e = (e0 + e1) + (e2 + e3) + exp2f((x80 - m) * LOG2E);

    float lse = m + log2f(e) * 0.6931471805599453f;
    int ctc = min(max(ct, 0), CC - 1);
    float xc = x[ctc];               // global re-fetch (L1-hot), not v[ctc]
    float cev = lse - xc;
    if (act) {
        ce[row] = cev;
        unsigned kv = (ct == 0) ? keymap(fg) : 0u;
        key[row] = kv;
        if (ct > 0) atomicAdd(&cnt_f[2], cev);
        if (ct == 0) atomicAdd(&lhist[kv >> 21], 1u);
    }
    __syncthreads();
    unsigned* hmy = hA + (blockIdx.x & 7) * 2048;
    for (int j = tid; j < 2048; j += 256)
        if (lhist[j]) atomicAdd(&hmy[j], lhist[j]);
}

// Fused selection (r13/r14-proven): scan-A (per-block, plain loads on
// prior-kernel hA) -> phase-B hist -> last-block scan+publish -> phase-C
// hist -> last-block scan+publish -> negative-CE sum -> fused final.
// Relaxed agent atomics + vmcnt(0) completion only. 128 co-resident blocks.
__global__ void __launch_bounds__(256) k_sel(const unsigned* __restrict__ key,
                                             const float* __restrict__ ce,
                                             int* __restrict__ cnt_i,
                                             float* __restrict__ cnt_f,
                                             const unsigned* __restrict__ hA,
                                             unsigned* __restrict__ hB,
                                             unsigned* __restrict__ hC,
                                             float* __restrict__ out) {
    __shared__ unsigned lh[2048];
    __shared__ int amLast;
    int tid = threadIdx.x;
    const uint4* k4 = (const uint4*)key;
    int n4 = ROWS / 4;

    unsigned T = 0xFFFFFFFFu; int eqS = 0;
    unsigned Kr = 3u * (unsigned)cnt_i[0];
    bool decided = (Kr == 0);            // no positives: select none
    unsigned prefixA = 0, remB = 0;
    if (!decided) {
        int binA = scan_bins<2048, false>(hA, Kr, &remB);
        if (binA < 0) { T = 0u; eqS = 0; decided = true; }  // select all
        else prefixA = (unsigned)binA;
    }

    if (!decided) {
        // ---- phase B: bits 20:10 within prefixA ----
        for (int j = tid; j < 2048; j += 256) lh[j] = 0;
        __syncthreads();
        for (int r = blockIdx.x * 256 + tid; r < n4; r += gridDim.x * 256) {
            uint4 k = k4[r];
            if ((k.x >> 21) == prefixA) atomicAdd(&lh[(k.x >> 10) & 0x7FFu], 1u);
            if ((k.y >> 21) == prefixA) atomicAdd(&lh[(k.y >> 10) & 0x7FFu], 1u);
            if ((k.z >> 21) == prefixA) atomicAdd(&lh[(k.z >> 10) & 0x7FFu], 1u);
            if ((k.w >> 21) == prefixA) atomicAdd(&lh[(k.w >> 10) & 0x7FFu], 1u);
        }
        __syncthreads();
        {
            unsigned* hmy = hB + (blockIdx.x & 7) * 2048;
            for (int j = tid; j < 2048; j += 256)
                if (lh[j]) atomicAdd(&hmy[j], lh[j]);
        }
        VMEM_DRAIN();
        if (tid == 0)
            amLast = (__hip_atomic_fetch_add((unsigned*)&cnt_i[12], 1u,
                       __ATOMIC_RELAXED, SCOPE_AGENT) == (unsigned)(gridDim.x - 1));
        __syncthreads();
        if (amLast) {
            unsigned remC; int binB = scan_bins<2048, true>(hB, remB, &remC);
            if (binB < 0) { binB = 0; remC = 0; }   // defensive
            if (tid == 0) {
                astore_i(&cnt_i[15], (int)((prefixA << 11) | (unsigned)binB));
                astore_i(&cnt_i[16], (int)remC);
                VMEM_DRAIN();
                astore_i(&cnt_i[14], 1);  // flagB
            }
        }
        if (tid == 0) {
            while (aload_i(&cnt_i[14]) == 0) __builtin_amdgcn_s_sleep(8);
        }
        __syncthreads();
        unsigned prefixAB = (unsigned)aload_i(&cnt_i[15]);
        unsigned KrC = (unsigned)aload_i(&cnt_i[16]);

        // ---- phase C: bits 9:0 within prefixAB ----
        for (int j = tid; j < 1024; j += 256) lh[j] = 0;
        __syncthreads();
        for (int r = blockIdx.x * 256 + tid; r < n4; r += gridDim.x * 256) {
            uint4 k = k4[r];
            if ((k.x >> 10) == prefixAB) atomicAdd(&lh[k.x & 0x3FFu], 1u);
            if ((k.y >> 10) == prefixAB) atomicAdd(&lh[k.y & 0x3FFu], 1u);
            if ((k.z >> 10) == prefixAB) atomicAdd(&lh[k.z & 0x3FFu], 1u);
            if ((k.w >> 10) == prefixAB) atomicAdd(&lh[k.w & 0x3FFu], 1u);
        }
        __syncthreads();
        {
            unsigned* hmy = hC + (blockIdx.x & 7) * 1024;
            for (int j = tid; j < 1024; j += 256)
                if (lh[j]) atomicAdd(&hmy[j], lh[j]);
        }
        VMEM_DRAIN();
        if (tid == 0)
            amLast = (__hip_atomic_fetch_add((unsigned*)&cnt_i[17], 1u,
                       __ATOMIC_RELAXED, SCOPE_AGENT) == (unsigned)(gridDim.x - 1));
        __syncthreads();
        if (amLast) {
            unsigned remD; int binC = scan_bins<1024, true>(hC, KrC, &remD);
            if (binC < 0) { binC = 0; remD = 0; }   // defensive
            if (tid == 0) {
                astore_i(&cnt_i[10], (int)((prefixAB << 10) | (unsigned)binC));
                astore_i(&cnt_i[11], (int)remD);
                VMEM_DRAIN();
                astore_i(&cnt_i[21], 1);  // flagD
            }
        }
        if (tid == 0) {
            while (aload_i(&cnt_i[21]) == 0) __builtin_amdgcn_s_sleep(8);
        }
        __syncthreads();
        T = (unsigned)aload_i(&cnt_i[10]);
        eqS = aload_i(&cnt_i[11]);
    }

    // ---- negative-CE sum over selected (key > T, or == T up to eqS) ----
    float s = 0.f; int c = 0;
    for (int r = blockIdx.x * 256 + tid; r < n4; r += gridDim.x * 256) {
        uint4 k = k4[r];
        #define DO_ONE(comp, idx) { \
            unsigned kk = k.comp; \
            if (kk) { \
                bool selr = false; \
                if (kk > T) selr = true; \
                else if (kk == T) { int slot = atomicAdd(&cnt_i[5], 1); selr = slot < eqS; } \
                if (selr) { s += ce[4 * r + idx]; c++; } \
            } }
        DO_ONE(x, 0) DO_ONE(y, 1) DO_ONE(z, 2) DO_ONE(w, 3)
        #undef DO_ONE
    }
    __shared__ float rs[256]; __shared__ int rc[256];
    rs[tid] = s; rc[tid] = c; __syncthreads();
    for (int st = 128; st > 0; st >>= 1) {
        if (tid < st) { rs[tid] += rs[tid + st]; rc[tid] += rc[tid + st]; }
        __syncthreads();
    }
    if (tid == 0) {
        if (rs[0] != 0.f) atomicAdd(&cnt_f[3], rs[0]);
        if (rc[0])        atomicAdd(&cnt_i[4], rc[0]);
    }
    VMEM_DRAIN();   // my partial sums are at the coherence point
    if (tid == 0 &&
        __hip_atomic_fetch_add((unsigned*)&cnt_i[13], 1u,
            __ATOMIC_RELAXED, SCOPE_AGENT) == (unsigned)(gridDim.x - 1)) {
        int np = aload_i(&cnt_i[0]);
        int nn = aload_i(&cnt_i[4]);
        float f1 = aload_f(&cnt_f[1]);
        float f2 = aload_f(&cnt_f[2]);
        float f3 = aload_f(&cnt_f[3]);
        out[0] = f1 / (float)max(np, 1);
        out[1] = (f2 + f3) / (float)max(np + nn, 1);
    }
}

extern "C" void kernel_launch(void* const* d_in, const int* in_sizes, int n_in,
                              void* d_out, int out_size, void* d_ws, size_t ws_size,
                              hipStream_t stream) {
    const float* loc    = (const float*)d_in[0];
    const float* conf   = (const float*)d_in[1];
    const float* priors = (const float*)d_in[2];
    const float* gt     = (const float*)d_in[3];
    const int*   labels = (const int*)d_in[4];
    float* out = (float*)d_out;
    int*      wi = (int*)d_ws;
    float*    wf = (float*)d_ws;
    unsigned* wu = (unsigned*)d_ws;
    unsigned long long* wbp = (unsigned long long*)(wi + W_BP);

    // no memset: k_best_prior zeroes cnt+hists; bp slots are plain-stored
    k_best_prior<<<dim3(NOBJ, BB, BPSPLIT), 256, 0, stream>>>(priors, gt, wbp, wi);
    k_match<<<dim3((PP + 255) / 256, BB), 256, 0, stream>>>(
        loc, priors, gt, labels, wbp, wi + W_CONF, wf, wi);
    k_conf<<<CONFBLK, 256, 0, stream>>>(conf, wi + W_CONF, wu + W_KEY,
                                        wf + W_CE, wf, wu + W_HA);
    k_sel<<<SELBLK, 256, 0, stream>>>(wu + W_KEY, wf + W_CE, wi, wf,
                                      wu + W_HA, wu + W_HB, wu + W_HC, out);
}